// Round 1
// baseline (3696.272 us; speedup 1.0000x reference)
//
#include <hip/hip_runtime.h>

#define SCALE 0.0625f  // 1/sqrt(256)

// ---------------------------------------------------------------------------
// Projection GEMM: C[M][256] = A[M][KD] @ W[KD][256], fp32.
// 64x64 tile, 256 threads, 4x4 micro-tile, K-step 16.
// ---------------------------------------------------------------------------
template<int KD>
__global__ __launch_bounds__(256) void proj_gemm(const float* __restrict__ A,
                                                 const float* __restrict__ W,
                                                 float* __restrict__ C) {
  __shared__ float As[16][68];
  __shared__ float Ws[16][68];
  const int t = threadIdx.x;
  const int tm = t >> 4, tn = t & 15;
  const int m0 = blockIdx.x * 64, n0 = blockIdx.y * 64;
  float acc[4][4] = {};
  for (int k0 = 0; k0 < KD; k0 += 16) {
    __syncthreads();
    {
      int r = t >> 2;
      int c4 = (t & 3) << 2;
      float4 a = *reinterpret_cast<const float4*>(&A[(size_t)(m0 + r) * KD + k0 + c4]);
      As[c4 + 0][r] = a.x; As[c4 + 1][r] = a.y; As[c4 + 2][r] = a.z; As[c4 + 3][r] = a.w;
      int kk = t >> 4;
      int w4 = (t & 15) << 2;
      *reinterpret_cast<float4*>(&Ws[kk][w4]) =
          *reinterpret_cast<const float4*>(&W[(size_t)(k0 + kk) * 256 + n0 + w4]);
    }
    __syncthreads();
#pragma unroll
    for (int kk = 0; kk < 16; ++kk) {
      float4 a = *reinterpret_cast<const float4*>(&As[kk][tm << 2]);
      float4 w = *reinterpret_cast<const float4*>(&Ws[kk][tn << 2]);
      float av[4] = {a.x, a.y, a.z, a.w};
      float wv[4] = {w.x, w.y, w.z, w.w};
#pragma unroll
      for (int i = 0; i < 4; ++i)
#pragma unroll
        for (int j = 0; j < 4; ++j) acc[i][j] += av[i] * wv[j];
    }
  }
#pragma unroll
  for (int i = 0; i < 4; ++i) {
    float4 o = make_float4(acc[i][0], acc[i][1], acc[i][2], acc[i][3]);
    *reinterpret_cast<float4*>(&C[(size_t)(m0 + (tm << 2) + i) * 256 + n0 + (tn << 2)]) = o;
  }
}

// ---------------------------------------------------------------------------
// Pass 1: per (b, k, m, rowblk64): online softmax stats (row max M, denom l)
// over all 576 keys.  Writes float2{M, l} per row.
// LDS tiles are XOR-swizzled at float4 granularity: slot = r*64 + (f4 ^ (r&7)).
// ---------------------------------------------------------------------------
__global__ __launch_bounds__(256) void attn_stats_kernel(const float* __restrict__ Qp,
                                                         const float* __restrict__ Kp,
                                                         float2* __restrict__ stats) {
  __shared__ float Qs[64 * 256];
  __shared__ float Ks[64 * 256];
  float4* Qs4 = reinterpret_cast<float4*>(Qs);
  float4* Ks4 = reinterpret_cast<float4*>(Ks);
  const int rb = blockIdx.x;   // 0..8
  const int km = blockIdx.y;   // k*10+m, 0..79
  const int b  = blockIdx.z;   // 0..3
  const int t  = threadIdx.x;
  const int tr = t >> 4, tc = t & 15;

  const float4* qsrc = reinterpret_cast<const float4*>(Qp + ((size_t)b * 576 + rb * 64) * 256);
#pragma unroll
  for (int i = 0; i < 16; ++i) {
    int f = t + (i << 8);
    int r = f >> 6, f4 = f & 63;
    Qs4[(r << 6) + (f4 ^ (r & 7))] = qsrc[f];
  }

  float m_run[4], l_run[4];
#pragma unroll
  for (int rr = 0; rr < 4; ++rr) { m_run[rr] = -1e30f; l_run[rr] = 0.f; }

  const float4* ksrc = reinterpret_cast<const float4*>(Kp + (size_t)km * 576 * 256);
  const int kq = tr & 7, kc = tc & 7;

  for (int jt = 0; jt < 9; ++jt) {
    __syncthreads();
#pragma unroll
    for (int i = 0; i < 16; ++i) {
      int f = t + (i << 8);
      int r = f >> 6, f4 = f & 63;
      Ks4[(r << 6) + (f4 ^ (r & 7))] = ksrc[jt * 4096 + f];
    }
    __syncthreads();

    float s[4][4] = {};
#pragma unroll 4
    for (int kk = 0; kk < 64; ++kk) {
      float4 qv[4], kv[4];
#pragma unroll
      for (int rr = 0; rr < 4; ++rr) qv[rr] = Qs4[((tr + 16 * rr) << 6) + (kk ^ kq)];
#pragma unroll
      for (int cc = 0; cc < 4; ++cc) kv[cc] = Ks4[((tc + 16 * cc) << 6) + (kk ^ kc)];
#pragma unroll
      for (int rr = 0; rr < 4; ++rr)
#pragma unroll
        for (int cc = 0; cc < 4; ++cc) {
          s[rr][cc] += qv[rr].x * kv[cc].x;
          s[rr][cc] += qv[rr].y * kv[cc].y;
          s[rr][cc] += qv[rr].z * kv[cc].z;
          s[rr][cc] += qv[rr].w * kv[cc].w;
        }
    }
#pragma unroll
    for (int rr = 0; rr < 4; ++rr) {
      float tmax = fmaxf(fmaxf(s[rr][0], s[rr][1]), fmaxf(s[rr][2], s[rr][3])) * SCALE;
#pragma unroll
      for (int off = 1; off < 16; off <<= 1) tmax = fmaxf(tmax, __shfl_xor(tmax, off, 64));
      float mnew = fmaxf(m_run[rr], tmax);
      float psum = 0.f;
#pragma unroll
      for (int cc = 0; cc < 4; ++cc) psum += __expf(s[rr][cc] * SCALE - mnew);
#pragma unroll
      for (int off = 1; off < 16; off <<= 1) psum += __shfl_xor(psum, off, 64);
      l_run[rr] = l_run[rr] * __expf(m_run[rr] - mnew) + psum;
      m_run[rr] = mnew;
    }
  }
  if (tc == 0) {
#pragma unroll
    for (int rr = 0; rr < 4; ++rr) {
      int n = rb * 64 + tr + 16 * rr;
      stats[(size_t)(b * 80 + km) * 576 + n] = make_float2(m_run[rr], l_run[rr]);
    }
  }
}

// ---------------------------------------------------------------------------
// Weight kernel: s[b,k,m] = mean_n 1/l ; w = p~ * s / (sum_m s + 1e-8)
// grid (k=8, b=4), 256 threads.
// ---------------------------------------------------------------------------
__global__ __launch_bounds__(256) void weight_kernel(const float2* __restrict__ stats,
                                                     const float* __restrict__ p,
                                                     float* __restrict__ w) {
  const int k = blockIdx.x, b = blockIdx.y;
  __shared__ float sm[10];
  __shared__ float red[4];
  const int t = threadIdx.x;
  for (int m = 0; m < 10; ++m) {
    float part = 0.f;
    for (int n = t; n < 576; n += 256) {
      float l = stats[(size_t)((b * 8 + k) * 10 + m) * 576 + n].y;
      part += 1.0f / l;
    }
#pragma unroll
    for (int off = 32; off; off >>= 1) part += __shfl_down(part, off, 64);
    if ((t & 63) == 0) red[t >> 6] = part;
    __syncthreads();
    if (t == 0) sm[m] = (red[0] + red[1] + red[2] + red[3]) * (1.0f / 576.0f);
    __syncthreads();
  }
  if (t == 0) {
    float tot = 0.f;
    for (int m = 0; m < 10; ++m) tot += sm[m];
    float pmax = fmaxf(fmaxf(p[0 * 8 + k], p[1 * 8 + k]), fmaxf(p[2 * 8 + k], p[3 * 8 + k]));
    float gate = (pmax >= 0.01f) ? p[b * 8 + k] : 0.0f;
    for (int m = 0; m < 10; ++m)
      w[(b * 8 + k) * 10 + m] = gate * sm[m] / (tot + 1e-8f);
  }
}

// ---------------------------------------------------------------------------
// Pass 2: per (b, kg, rowblk64): loop m in group; recompute S, P' =
// exp(S*scale - M) * (w_m / l), accumulate P' @ V into registers across m,
// write Rpart[b][kg].
// ---------------------------------------------------------------------------
__global__ __launch_bounds__(256) void attn_pv_kernel(const float* __restrict__ Qp,
                                                      const float* __restrict__ Kp,
                                                      const float* __restrict__ Vp,
                                                      const float2* __restrict__ stats,
                                                      const float* __restrict__ w,
                                                      float* __restrict__ Rpart,
                                                      int MG, int mpg) {
  __shared__ float Qs[64 * 256];
  __shared__ float KVs[64 * 256];
  __shared__ float Ps[64 * 68];
  float4* Qs4 = reinterpret_cast<float4*>(Qs);
  float4* KVs4 = reinterpret_cast<float4*>(KVs);
  const int rb = blockIdx.x;   // 0..8
  const int kg = blockIdx.y;   // k*MG + g
  const int b  = blockIdx.z;
  const int k  = kg / MG, g = kg % MG;
  const int m0 = g * mpg, m1 = m0 + mpg;
  const int t = threadIdx.x;
  const int tr = t >> 4, tc = t & 15;
  const int kq = tr & 7, kc = tc & 7;

  const float4* qsrc = reinterpret_cast<const float4*>(Qp + ((size_t)b * 576 + rb * 64) * 256);
#pragma unroll
  for (int i = 0; i < 16; ++i) {
    int f = t + (i << 8);
    int r = f >> 6, f4 = f & 63;
    Qs4[(r << 6) + (f4 ^ (r & 7))] = qsrc[f];
  }

  float acc[4][4][4] = {};

  for (int m = m0; m < m1; ++m) {
    const int km = k * 10 + m;
    const float wm = w[b * 80 + km];
    float coef[4], Mrow[4];
#pragma unroll
    for (int rr = 0; rr < 4; ++rr) {
      float2 st = stats[(size_t)(b * 80 + km) * 576 + rb * 64 + tr + 16 * rr];
      Mrow[rr] = st.x;
      coef[rr] = wm / st.y;
    }
    const float4* ksrc = reinterpret_cast<const float4*>(Kp + (size_t)km * 576 * 256);
    const float4* vsrc = reinterpret_cast<const float4*>(Vp + (size_t)km * 576 * 256);

    for (int jt = 0; jt < 9; ++jt) {
      __syncthreads();
#pragma unroll
      for (int i = 0; i < 16; ++i) {
        int f = t + (i << 8);
        int r = f >> 6, f4 = f & 63;
        KVs4[(r << 6) + (f4 ^ (r & 7))] = ksrc[jt * 4096 + f];
      }
      __syncthreads();

      float s[4][4] = {};
#pragma unroll 4
      for (int kk = 0; kk < 64; ++kk) {
        float4 qv[4], kv[4];
#pragma unroll
        for (int rr = 0; rr < 4; ++rr) qv[rr] = Qs4[((tr + 16 * rr) << 6) + (kk ^ kq)];
#pragma unroll
        for (int cc = 0; cc < 4; ++cc) kv[cc] = KVs4[((tc + 16 * cc) << 6) + (kk ^ kc)];
#pragma unroll
        for (int rr = 0; rr < 4; ++rr)
#pragma unroll
          for (int cc = 0; cc < 4; ++cc) {
            s[rr][cc] += qv[rr].x * kv[cc].x;
            s[rr][cc] += qv[rr].y * kv[cc].y;
            s[rr][cc] += qv[rr].z * kv[cc].z;
            s[rr][cc] += qv[rr].w * kv[cc].w;
          }
      }
#pragma unroll
      for (int rr = 0; rr < 4; ++rr)
#pragma unroll
        for (int cc = 0; cc < 4; ++cc) {
          float pv = __expf(s[rr][cc] * SCALE - Mrow[rr]) * coef[rr];
          Ps[(tr + 16 * rr) * 68 + tc + 16 * cc] = pv;
        }
      __syncthreads();
#pragma unroll
      for (int i = 0; i < 16; ++i) {
        int f = t + (i << 8);
        int r = f >> 6, f4 = f & 63;
        KVs4[(r << 6) + (f4 ^ (r & 7))] = vsrc[jt * 4096 + f];
      }
      __syncthreads();

#pragma unroll 2
      for (int j = 0; j < 64; ++j) {
        float pr[4];
#pragma unroll
        for (int rr = 0; rr < 4; ++rr) pr[rr] = Ps[(tr + 16 * rr) * 68 + j];
        const int jx = j & 7;
#pragma unroll
        for (int ch = 0; ch < 4; ++ch) {
          float4 v = KVs4[(j << 6) + (((ch << 4) + tc) ^ jx)];
#pragma unroll
          for (int rr = 0; rr < 4; ++rr) {
            acc[rr][ch][0] += pr[rr] * v.x;
            acc[rr][ch][1] += pr[rr] * v.y;
            acc[rr][ch][2] += pr[rr] * v.z;
            acc[rr][ch][3] += pr[rr] * v.w;
          }
        }
      }
    }
  }

  const int G = 8 * MG;
  float* dst = Rpart + ((size_t)(b * G + kg) * 576 + rb * 64) * 256;
#pragma unroll
  for (int rr = 0; rr < 4; ++rr)
#pragma unroll
    for (int ch = 0; ch < 4; ++ch) {
      float4 o = make_float4(acc[rr][ch][0], acc[rr][ch][1], acc[rr][ch][2], acc[rr][ch][3]);
      *reinterpret_cast<float4*>(&dst[(tr + 16 * rr) * 256 + (ch << 6) + (tc << 2)]) = o;
    }
}

// ---------------------------------------------------------------------------
// Final reduce over groups + transpose (n,d)->(d,n).
// ---------------------------------------------------------------------------
__global__ __launch_bounds__(256) void reduce_out(const float* __restrict__ Rpart,
                                                  float* __restrict__ out, int G) {
  int idx = blockIdx.x * 256 + threadIdx.x;  // 589824 total
  int d = idx & 255;
  int rest = idx >> 8;   // b*576 + n
  int n = rest % 576;
  int b = rest / 576;
  float acc = 0.f;
  for (int g = 0; g < G; ++g)
    acc += Rpart[((size_t)(b * G + g) * 576 + n) * 256 + d];
  out[((size_t)b * 256 + d) * 576 + n] = acc;
}

// ---------------------------------------------------------------------------
extern "C" void kernel_launch(void* const* d_in, const int* in_sizes, int n_in,
                              void* d_out, int out_size, void* d_ws, size_t ws_size,
                              hipStream_t stream) {
  const float* Q   = (const float*)d_in[0];
  const float* dbk = (const float*)d_in[1];
  const float* dbv = (const float*)d_in[2];
  const float* p   = (const float*)d_in[3];
  const float* Wq  = (const float*)d_in[4];
  const float* Wk  = (const float*)d_in[5];
  const float* Wv  = (const float*)d_in[6];
  float* out = (float*)d_out;
  float* ws  = (float*)d_ws;

  float*  qp    = ws;                       // 2304 x 256
  float*  kp    = ws + 589824;              // 46080 x 256
  float*  vp    = ws + 12386304;            // 46080 x 256
  float2* stats = (float2*)(ws + 24182784); // 320 x 576 float2
  float*  wbuf  = ws + 24551424;            // 320
  float*  rpart = ws + 24551744;            // G x B x 576 x 256

  int MG = 1;
  {
    const size_t base = 24551744;
    const int cands[4] = {10, 5, 2, 1};
    for (int i = 0; i < 4; ++i) {
      size_t need = (base + (size_t)cands[i] * 4718592) * 4;
      if (need <= ws_size) { MG = cands[i]; break; }
    }
  }
  const int mpg = 10 / MG;

  proj_gemm<416><<<dim3(36, 4), 256, 0, stream>>>(Q, Wq, qp);
  proj_gemm<416><<<dim3(720, 4), 256, 0, stream>>>(dbk, Wk, kp);
  proj_gemm<384><<<dim3(720, 4), 256, 0, stream>>>(dbv, Wv, vp);
  attn_stats_kernel<<<dim3(9, 80, 4), 256, 0, stream>>>(qp, kp, stats);
  weight_kernel<<<dim3(8, 4), 256, 0, stream>>>(stats, p, wbuf);
  attn_pv_kernel<<<dim3(9, 8 * MG, 4), 256, 0, stream>>>(qp, kp, vp, stats, wbuf, rpart, MG, mpg);
  reduce_out<<<dim3(2304), 256, 0, stream>>>(rpart, out, 8 * MG);
}

// Round 2
// 989.110 us; speedup vs baseline: 3.7370x; 3.7370x over previous
//
#include <hip/hip_runtime.h>

typedef float f32x4 __attribute__((ext_vector_type(4)));
typedef short bf16x8 __attribute__((ext_vector_type(8)));
typedef unsigned short u16;
typedef unsigned int u32;

#define SCALE 0.0625f
#define MFMA16(a, b, c) __builtin_amdgcn_mfma_f32_16x16x32_bf16((a), (b), (c), 0, 0, 0)

__device__ inline u16 f2bf(float x) {
  u32 u = __float_as_uint(x);
  u32 r = u + 0x7FFFu + ((u >> 16) & 1u);
  return (u16)(r >> 16);
}
__device__ inline float bf2f(u16 h) { return __uint_as_float(((u32)h) << 16); }

// ---------------------------------------------------------------------------
// Transpose+split W matrices: W[k][n] fp32 -> Wt_hi/lo[n][k] bf16.
// ---------------------------------------------------------------------------
__global__ __launch_bounds__(256) void convert_w(
    const float* __restrict__ Wq, const float* __restrict__ Wk, const float* __restrict__ Wv,
    u16* __restrict__ qh, u16* __restrict__ qlo2, u16* __restrict__ kh, u16* __restrict__ klo2,
    u16* __restrict__ vh, u16* __restrict__ vlo2) {
  int idx = blockIdx.x * 256 + threadIdx.x;
  const float* src;
  u16 *dh, *dl;
  int KD;
  const int nq = 416 * 256;
  if (idx < nq) {
    src = Wq; dh = qh; dl = qlo2; KD = 416;
  } else if (idx < 2 * nq) {
    idx -= nq; src = Wk; dh = kh; dl = klo2; KD = 416;
  } else {
    idx -= 2 * nq;
    if (idx >= 384 * 256) return;
    src = Wv; dh = vh; dl = vlo2; KD = 384;
  }
  int k = idx >> 8, n = idx & 255;
  float x = src[idx];
  u16 h = f2bf(x);
  dh[n * KD + k] = h;
  dl[n * KD + k] = f2bf(x - bf2f(h));
}

// ---------------------------------------------------------------------------
// Projection GEMM, split-bf16 MFMA: C[m][256] = A[m][KD] @ W[KD][256].
// Block: 64 rows x 256 cols, 4 waves (each 16 rows x 256 cols), K-step 32.
// Outputs bf16 hi/lo; TRANS_OUT writes V^T layout [km][256][576].
// ---------------------------------------------------------------------------
template <int KD, bool TRANS_OUT>
__global__ __launch_bounds__(256, 2) void proj_mfma(
    const float* __restrict__ A, const u16* __restrict__ wth, const u16* __restrict__ wtl,
    u16* __restrict__ oh, u16* __restrict__ ol) {
  __shared__ u16 Ah[64 * 32], Al[64 * 32];    // [row][32k], chunk swz (c+(row>>1))&3
  __shared__ u16 Wh[256 * 32], Wl[256 * 32];  // [n][32k], same swz
  const int t = threadIdx.x;
  const int w = t >> 6, l = t & 63;
  const int lr = l & 15, lk = l >> 4;
  const int m0 = blockIdx.x * 64;
  f32x4 acc[16];
#pragma unroll
  for (int i = 0; i < 16; ++i) acc[i] = {};
  const int arow = t >> 2, ac = t & 3;
  const int acp = (ac + (arow >> 1)) & 3;
  for (int k0 = 0; k0 < KD; k0 += 32) {
    __syncthreads();
    {
      const float* s1 = A + (size_t)(m0 + arow) * KD + k0 + ac * 8;
      float4 f1 = *(const float4*)s1;
      float4 f2 = *(const float4*)(s1 + 4);
      float fs[8] = {f1.x, f1.y, f1.z, f1.w, f2.x, f2.y, f2.z, f2.w};
      bf16x8 hv, lv;
#pragma unroll
      for (int j = 0; j < 8; ++j) {
        u16 h = f2bf(fs[j]);
        hv[j] = (short)h;
        lv[j] = (short)f2bf(fs[j] - bf2f(h));
      }
      *(bf16x8*)(Ah + arow * 32 + acp * 8) = hv;
      *(bf16x8*)(Al + arow * 32 + acp * 8) = lv;
#pragma unroll
      for (int i = 0; i < 4; ++i) {
        int ch = t + i * 256;
        int n = ch >> 2, c = ch & 3;
        int cp = (c + (n >> 1)) & 3;
        *(bf16x8*)(Wh + n * 32 + cp * 8) = *(const bf16x8*)(wth + (size_t)n * KD + k0 + c * 8);
        *(bf16x8*)(Wl + n * 32 + cp * 8) = *(const bf16x8*)(wtl + (size_t)n * KD + k0 + c * 8);
      }
    }
    __syncthreads();
    const int row = w * 16 + lr;
    const int rcp = (lk + (row >> 1)) & 3;
    bf16x8 ah = *(const bf16x8*)(Ah + row * 32 + rcp * 8);
    bf16x8 al = *(const bf16x8*)(Al + row * 32 + rcp * 8);
#pragma unroll
    for (int fc = 0; fc < 16; ++fc) {
      int n = lr + 16 * fc;
      int cp = (lk + (n >> 1)) & 3;
      bf16x8 bh = *(const bf16x8*)(Wh + n * 32 + cp * 8);
      bf16x8 bl = *(const bf16x8*)(Wl + n * 32 + cp * 8);
      acc[fc] = MFMA16(ah, bh, acc[fc]);
      acc[fc] = MFMA16(ah, bl, acc[fc]);
      acc[fc] = MFMA16(al, bh, acc[fc]);
    }
  }
  if (!TRANS_OUT) {
#pragma unroll
    for (int fc = 0; fc < 16; ++fc) {
      int n = lr + 16 * fc;
#pragma unroll
      for (int r = 0; r < 4; ++r) {
        int m = m0 + w * 16 + lk * 4 + r;
        float v = acc[fc][r];
        u16 h = f2bf(v);
        oh[(size_t)m * 256 + n] = h;
        ol[(size_t)m * 256 + n] = f2bf(v - bf2f(h));
      }
    }
  } else {
    const int km = m0 / 576;
    const int j0 = (m0 % 576) + w * 16 + lk * 4;
#pragma unroll
    for (int fc = 0; fc < 16; ++fc) {
      int n = lr + 16 * fc;
      u16 hs[4], ls[4];
#pragma unroll
      for (int r = 0; r < 4; ++r) {
        float v = acc[fc][r];
        u16 h = f2bf(v);
        hs[r] = h;
        ls[r] = f2bf(v - bf2f(h));
      }
      size_t base = ((size_t)km * 256 + n) * 576 + j0;
      *(ushort4*)(oh + base) = make_ushort4(hs[0], hs[1], hs[2], hs[3]);
      *(ushort4*)(ol + base) = make_ushort4(ls[0], ls[1], ls[2], ls[3]);
    }
  }
}

// ---------------------------------------------------------------------------
// Flash attention per (b, km, qtile64): S = Q K^T (split-bf16 MFMA), online
// softmax, R = P V (split-bf16 MFMA).  Writes R^T [b,km][d][n] and 1/l.
// ---------------------------------------------------------------------------
__global__ __launch_bounds__(256, 2) void attn_kernel(
    const u16* __restrict__ qhi, const u16* __restrict__ qlo,
    const u16* __restrict__ khi, const u16* __restrict__ klo,
    const u16* __restrict__ vthi, const u16* __restrict__ vtlo,
    float* __restrict__ rpartT, float* __restrict__ invl) {
  __shared__ u16 Kh[32 * 256], Kl[32 * 256];  // [key][256d], chunk swz c^(key&7)
  __shared__ u16 Vh[256 * 32], Vl[256 * 32];  // [d][32j], chunk swz (c+(d>>1))&3
  __shared__ u16 Pb[4][2][16 * 40];           // per-wave P hi/lo, row stride 40
  const int t = threadIdx.x;
  const int w = t >> 6, l = t & 63;
  const int lr = l & 15, lk = l >> 4;
  const int qb = blockIdx.x % 9, b = blockIdx.x / 9;
  const int km = blockIdx.y;
  const int qw = qb * 64 + w * 16;

  bf16x8 qh[8], ql[8];
  {
    const u16* ph = qhi + ((size_t)(b * 576 + qw + lr)) * 256 + lk * 8;
    const u16* pl = qlo + ((size_t)(b * 576 + qw + lr)) * 256 + lk * 8;
#pragma unroll
    for (int s = 0; s < 8; ++s) {
      qh[s] = *(const bf16x8*)(ph + s * 32);
      ql[s] = *(const bf16x8*)(pl + s * 32);
    }
  }

  f32x4 o[16];
#pragma unroll
  for (int i = 0; i < 16; ++i) o[i] = {};
  float m_run[4] = {-1e30f, -1e30f, -1e30f, -1e30f};
  float l_run[4] = {0.f, 0.f, 0.f, 0.f};

  const size_t kbase = (size_t)km * 576 * 256;
  u16* phw = &Pb[w][0][0];
  u16* plw = &Pb[w][1][0];
  const int x0 = lr & 7;

  for (int kt = 0; kt < 18; ++kt) {
    __syncthreads();
    {
      const int j0 = kt * 32;
#pragma unroll
      for (int i = 0; i < 4; ++i) {
        int ch = t + i * 256;
        int row = ch >> 5, c = ch & 31;
        int cp = c ^ (row & 7);
        *(bf16x8*)(Kh + row * 256 + cp * 8) =
            *(const bf16x8*)(khi + kbase + (size_t)(j0 + row) * 256 + c * 8);
        *(bf16x8*)(Kl + row * 256 + cp * 8) =
            *(const bf16x8*)(klo + kbase + (size_t)(j0 + row) * 256 + c * 8);
      }
#pragma unroll
      for (int i = 0; i < 4; ++i) {
        int ch = t + i * 256;
        int d = ch >> 2, c = ch & 3;
        int cp = (c + (d >> 1)) & 3;
        *(bf16x8*)(Vh + d * 32 + cp * 8) =
            *(const bf16x8*)(vthi + kbase + (size_t)d * 576 + j0 + c * 8);
        *(bf16x8*)(Vl + d * 32 + cp * 8) =
            *(const bf16x8*)(vtlo + kbase + (size_t)d * 576 + j0 + c * 8);
      }
    }
    __syncthreads();

    f32x4 s0 = {}, s1 = {};
#pragma unroll
    for (int s = 0; s < 8; ++s) {
      int cl = s * 4 + lk;
      bf16x8 bh0 = *(const bf16x8*)(Kh + lr * 256 + (cl ^ x0) * 8);
      bf16x8 bl0 = *(const bf16x8*)(Kl + lr * 256 + (cl ^ x0) * 8);
      bf16x8 bh1 = *(const bf16x8*)(Kh + (lr + 16) * 256 + (cl ^ x0) * 8);
      bf16x8 bl1 = *(const bf16x8*)(Kl + (lr + 16) * 256 + (cl ^ x0) * 8);
      s0 = MFMA16(qh[s], bh0, s0);
      s0 = MFMA16(qh[s], bl0, s0);
      s0 = MFMA16(ql[s], bh0, s0);
      s1 = MFMA16(qh[s], bh1, s1);
      s1 = MFMA16(qh[s], bl1, s1);
      s1 = MFMA16(ql[s], bh1, s1);
    }

    float p0[4], p1[4], fs4[4];
#pragma unroll
    for (int r = 0; r < 4; ++r) {
      float a0 = s0[r] * SCALE, a1 = s1[r] * SCALE;
      float mx = fmaxf(a0, a1);
      mx = fmaxf(mx, __shfl_xor(mx, 1, 64));
      mx = fmaxf(mx, __shfl_xor(mx, 2, 64));
      mx = fmaxf(mx, __shfl_xor(mx, 4, 64));
      mx = fmaxf(mx, __shfl_xor(mx, 8, 64));
      float mn = fmaxf(m_run[r], mx);
      float e0 = __expf(a0 - mn), e1 = __expf(a1 - mn);
      float ps = e0 + e1;
      ps += __shfl_xor(ps, 1, 64);
      ps += __shfl_xor(ps, 2, 64);
      ps += __shfl_xor(ps, 4, 64);
      ps += __shfl_xor(ps, 8, 64);
      float f = __expf(m_run[r] - mn);
      l_run[r] = l_run[r] * f + ps;
      m_run[r] = mn;
      fs4[r] = f;
      p0[r] = e0;
      p1[r] = e1;
    }
#pragma unroll
    for (int i = 0; i < 16; ++i) {
      o[i][0] *= fs4[0];
      o[i][1] *= fs4[1];
      o[i][2] *= fs4[2];
      o[i][3] *= fs4[3];
    }
#pragma unroll
    for (int r = 0; r < 4; ++r) {
      int row = lk * 4 + r;
      u16 h0 = f2bf(p0[r]);
      u16 h1 = f2bf(p1[r]);
      phw[row * 40 + lr] = h0;
      phw[row * 40 + lr + 16] = h1;
      plw[row * 40 + lr] = f2bf(p0[r] - bf2f(h0));
      plw[row * 40 + lr + 16] = f2bf(p1[r] - bf2f(h1));
    }
    bf16x8 pah = *(const bf16x8*)(phw + lr * 40 + lk * 8);
    bf16x8 pal = *(const bf16x8*)(plw + lr * 40 + lk * 8);
#pragma unroll
    for (int fd = 0; fd < 16; ++fd) {
      int d = lr + 16 * fd;
      int cp = (lk + (d >> 1)) & 3;
      bf16x8 vh_ = *(const bf16x8*)(Vh + d * 32 + cp * 8);
      bf16x8 vl_ = *(const bf16x8*)(Vl + d * 32 + cp * 8);
      o[fd] = MFMA16(pah, vh_, o[fd]);
      o[fd] = MFMA16(pah, vl_, o[fd]);
      o[fd] = MFMA16(pal, vh_, o[fd]);
    }
  }

  float inv4[4];
#pragma unroll
  for (int r = 0; r < 4; ++r) inv4[r] = 1.0f / l_run[r];
  float* dst = rpartT + (size_t)(b * 80 + km) * (256 * 576);
#pragma unroll
  for (int fd = 0; fd < 16; ++fd) {
    int d = lr + 16 * fd;
    f32x4 vv;
    vv[0] = o[fd][0] * inv4[0];
    vv[1] = o[fd][1] * inv4[1];
    vv[2] = o[fd][2] * inv4[2];
    vv[3] = o[fd][3] * inv4[3];
    *(f32x4*)(dst + (size_t)d * 576 + qw + lk * 4) = vv;
  }
  if (lr == 0) {
#pragma unroll
    for (int r = 0; r < 4; ++r)
      invl[(size_t)(b * 80 + km) * 576 + qw + lk * 4 + r] = inv4[r];
  }
}

// ---------------------------------------------------------------------------
// Weights: s[b,k,m] = mean_n 1/l ; w = gate(p) * s / (sum_m s + 1e-8)
// ---------------------------------------------------------------------------
__global__ __launch_bounds__(256) void weight_kernel(const float* __restrict__ invl,
                                                     const float* __restrict__ p,
                                                     float* __restrict__ wout) {
  const int k = blockIdx.x, b = blockIdx.y;
  __shared__ float sm[10];
  __shared__ float red[4];
  const int t = threadIdx.x;
  for (int m = 0; m < 10; ++m) {
    float part = 0.f;
    for (int n = t; n < 576; n += 256)
      part += invl[(size_t)((b * 8 + k) * 10 + m) * 576 + n];
#pragma unroll
    for (int off = 32; off; off >>= 1) part += __shfl_down(part, off, 64);
    if ((t & 63) == 0) red[t >> 6] = part;
    __syncthreads();
    if (t == 0) sm[m] = (red[0] + red[1] + red[2] + red[3]) * (1.0f / 576.0f);
    __syncthreads();
  }
  if (t == 0) {
    float tot = 0.f;
    for (int m = 0; m < 10; ++m) tot += sm[m];
    float pmax = fmaxf(fmaxf(p[0 * 8 + k], p[1 * 8 + k]), fmaxf(p[2 * 8 + k], p[3 * 8 + k]));
    float gate = (pmax >= 0.01f) ? p[b * 8 + k] : 0.0f;
    for (int m = 0; m < 10; ++m)
      wout[(b * 8 + k) * 10 + m] = gate * sm[m] / (tot + 1e-8f);
  }
}

// ---------------------------------------------------------------------------
// out[b][d][n] = sum_km w[b,km] * rpartT[b,km][d][n]   (fully coalesced)
// ---------------------------------------------------------------------------
__global__ __launch_bounds__(256) void reduce_out_k(const float* __restrict__ rpartT,
                                                    const float* __restrict__ wbuf,
                                                    float* __restrict__ out) {
  int idx = blockIdx.x * 256 + threadIdx.x;
  int b = idx / 147456;
  size_t off = (size_t)(idx % 147456);
  const float* base = rpartT + (size_t)b * 80 * 147456 + off;
  const float* wp = wbuf + b * 80;
  float acc = 0.f;
#pragma unroll 8
  for (int g = 0; g < 80; ++g) acc += wp[g] * base[(size_t)g * 147456];
  out[idx] = acc;
}

// ---------------------------------------------------------------------------
extern "C" void kernel_launch(void* const* d_in, const int* in_sizes, int n_in,
                              void* d_out, int out_size, void* d_ws, size_t ws_size,
                              hipStream_t stream) {
  const float* Q = (const float*)d_in[0];
  const float* dbk = (const float*)d_in[1];
  const float* dbv = (const float*)d_in[2];
  const float* p = (const float*)d_in[3];
  const float* Wq = (const float*)d_in[4];
  const float* Wk = (const float*)d_in[5];
  const float* Wv = (const float*)d_in[6];
  float* out = (float*)d_out;
  char* ws = (char*)d_ws;

  u16* qhi = (u16*)(ws);                    // 2304x256 u16 = 1,179,648 B
  u16* qlo = (u16*)(ws + 1179648);
  u16* khi = (u16*)(ws + 2359296);          // 46080x256 u16 = 23,592,960 B
  u16* klo = (u16*)(ws + 25952256);
  u16* vthi = (u16*)(ws + 49545216);        // [km][256][576] u16
  u16* vtlo = (u16*)(ws + 73138176);
  float* invl = (float*)(ws + 96731136);    // 320x576 f32
  float* wbuf = (float*)(ws + 97468416);    // 320 f32
  float* rpartT = (float*)(ws + 97469696);  // 320x256x576 f32 = 188,743,680 B
  // W^T hi/lo aliased into rpartT region (consumed by proj before attn writes)
  u16* wqh = (u16*)(ws + 97469696);
  u16* wql = wqh + 106496;
  u16* wkh = wql + 106496;
  u16* wkl = wkh + 106496;
  u16* wvh = wkl + 106496;
  u16* wvl = wvh + 98304;

  convert_w<<<1216, 256, 0, stream>>>(Wq, Wk, Wv, wqh, wql, wkh, wkl, wvh, wvl);
  proj_mfma<416, false><<<36, 256, 0, stream>>>(Q, wqh, wql, qhi, qlo);
  proj_mfma<416, false><<<720, 256, 0, stream>>>(dbk, wkh, wkl, khi, klo);
  proj_mfma<384, true><<<720, 256, 0, stream>>>(dbv, wvh, wvl, vthi, vtlo);
  attn_kernel<<<dim3(36, 80), 256, 0, stream>>>(qhi, qlo, khi, klo, vthi, vtlo, rpartT, invl);
  weight_kernel<<<dim3(8, 4), 256, 0, stream>>>(invl, p, wbuf);
  reduce_out_k<<<2304, 256, 0, stream>>>(rpartT, wbuf, out);
}

// Round 3
// 900.949 us; speedup vs baseline: 4.1026x; 1.0979x over previous
//
#include <hip/hip_runtime.h>

typedef float f32x4 __attribute__((ext_vector_type(4)));
typedef short bf16x8 __attribute__((ext_vector_type(8)));
typedef unsigned short u16;
typedef unsigned int u32;

#define SCALE 0.0625f
#define MFMA16(a, b, c) __builtin_amdgcn_mfma_f32_16x16x32_bf16((a), (b), (c), 0, 0, 0)

__device__ inline u16 f2bf(float x) {
  u32 u = __float_as_uint(x);
  u32 r = u + 0x7FFFu + ((u >> 16) & 1u);
  return (u16)(r >> 16);
}
__device__ inline float bf2f(u16 h) { return __uint_as_float(((u32)h) << 16); }

// ---------------------------------------------------------------------------
// Transpose+split W matrices: W[k][n] fp32 -> Wt_hi/lo[n][k] bf16.
// ---------------------------------------------------------------------------
__global__ __launch_bounds__(256) void convert_w(
    const float* __restrict__ Wq, const float* __restrict__ Wk, const float* __restrict__ Wv,
    u16* __restrict__ qh, u16* __restrict__ qlo2, u16* __restrict__ kh, u16* __restrict__ klo2,
    u16* __restrict__ vh, u16* __restrict__ vlo2) {
  int idx = blockIdx.x * 256 + threadIdx.x;
  const float* src;
  u16 *dh, *dl;
  int KD;
  const int nq = 416 * 256;
  if (idx < nq) {
    src = Wq; dh = qh; dl = qlo2; KD = 416;
  } else if (idx < 2 * nq) {
    idx -= nq; src = Wk; dh = kh; dl = klo2; KD = 416;
  } else {
    idx -= 2 * nq;
    if (idx >= 384 * 256) return;
    src = Wv; dh = vh; dl = vlo2; KD = 384;
  }
  int k = idx >> 8, n = idx & 255;
  float x = src[idx];
  u16 h = f2bf(x);
  dh[n * KD + k] = h;
  dl[n * KD + k] = f2bf(x - bf2f(h));
}

// ---------------------------------------------------------------------------
// Projection GEMM, split-bf16 MFMA: C[m][256] = A[m][KD] @ W[KD][256].
// ---------------------------------------------------------------------------
template <int KD, bool TRANS_OUT>
__global__ __launch_bounds__(256, 3) void proj_mfma(
    const float* __restrict__ A, const u16* __restrict__ wth, const u16* __restrict__ wtl,
    u16* __restrict__ oh, u16* __restrict__ ol) {
  __shared__ u16 Ah[64 * 32], Al[64 * 32];
  __shared__ u16 Wh[256 * 32], Wl[256 * 32];
  const int t = threadIdx.x;
  const int w = t >> 6, l = t & 63;
  const int lr = l & 15, lk = l >> 4;
  const int m0 = blockIdx.x * 64;
  f32x4 acc[16];
#pragma unroll
  for (int i = 0; i < 16; ++i) acc[i] = {};
  const int arow = t >> 2, ac = t & 3;
  const int acp = (ac + (arow >> 1)) & 3;
  for (int k0 = 0; k0 < KD; k0 += 32) {
    __syncthreads();
    {
      const float* s1 = A + (size_t)(m0 + arow) * KD + k0 + ac * 8;
      float4 f1 = *(const float4*)s1;
      float4 f2 = *(const float4*)(s1 + 4);
      float fs[8] = {f1.x, f1.y, f1.z, f1.w, f2.x, f2.y, f2.z, f2.w};
      bf16x8 hv, lv;
#pragma unroll
      for (int j = 0; j < 8; ++j) {
        u16 h = f2bf(fs[j]);
        hv[j] = (short)h;
        lv[j] = (short)f2bf(fs[j] - bf2f(h));
      }
      *(bf16x8*)(Ah + arow * 32 + acp * 8) = hv;
      *(bf16x8*)(Al + arow * 32 + acp * 8) = lv;
#pragma unroll
      for (int i = 0; i < 4; ++i) {
        int ch = t + i * 256;
        int n = ch >> 2, c = ch & 3;
        int cp = (c + (n >> 1)) & 3;
        *(bf16x8*)(Wh + n * 32 + cp * 8) = *(const bf16x8*)(wth + (size_t)n * KD + k0 + c * 8);
        *(bf16x8*)(Wl + n * 32 + cp * 8) = *(const bf16x8*)(wtl + (size_t)n * KD + k0 + c * 8);
      }
    }
    __syncthreads();
    const int row = w * 16 + lr;
    const int rcp = (lk + (row >> 1)) & 3;
    bf16x8 ah = *(const bf16x8*)(Ah + row * 32 + rcp * 8);
    bf16x8 al = *(const bf16x8*)(Al + row * 32 + rcp * 8);
#pragma unroll
    for (int fc = 0; fc < 16; ++fc) {
      int n = lr + 16 * fc;
      int cp = (lk + (n >> 1)) & 3;
      bf16x8 bh = *(const bf16x8*)(Wh + n * 32 + cp * 8);
      bf16x8 bl = *(const bf16x8*)(Wl + n * 32 + cp * 8);
      acc[fc] = MFMA16(ah, bh, acc[fc]);
      acc[fc] = MFMA16(ah, bl, acc[fc]);
      acc[fc] = MFMA16(al, bh, acc[fc]);
    }
  }
  if (!TRANS_OUT) {
#pragma unroll
    for (int fc = 0; fc < 16; ++fc) {
      int n = lr + 16 * fc;
#pragma unroll
      for (int r = 0; r < 4; ++r) {
        int m = m0 + w * 16 + lk * 4 + r;
        float v = acc[fc][r];
        u16 h = f2bf(v);
        oh[(size_t)m * 256 + n] = h;
        ol[(size_t)m * 256 + n] = f2bf(v - bf2f(h));
      }
    }
  } else {
    const int km = m0 / 576;
    const int j0 = (m0 % 576) + w * 16 + lk * 4;
#pragma unroll
    for (int fc = 0; fc < 16; ++fc) {
      int n = lr + 16 * fc;
      u16 hs[4], ls[4];
#pragma unroll
      for (int r = 0; r < 4; ++r) {
        float v = acc[fc][r];
        u16 h = f2bf(v);
        hs[r] = h;
        ls[r] = f2bf(v - bf2f(h));
      }
      size_t base = ((size_t)km * 256 + n) * 576 + j0;
      *(ushort4*)(oh + base) = make_ushort4(hs[0], hs[1], hs[2], hs[3]);
      *(ushort4*)(ol + base) = make_ushort4(ls[0], ls[1], ls[2], ls[3]);
    }
  }
}

// ---------------------------------------------------------------------------
// Flash attention per (b, km, qtile64), m==0 softmax (bounded logits):
// P = exp(S*scale); l,max accumulated per-lane, reduced once at end.
// Reg-prefetch staging (T14); XCD km-cluster swizzle; setprio around MFMA.
// ---------------------------------------------------------------------------
__global__ __launch_bounds__(256, 2) void attn_kernel(
    const u16* __restrict__ qhi, const u16* __restrict__ qlo,
    const u16* __restrict__ khi, const u16* __restrict__ klo,
    const u16* __restrict__ vthi, const u16* __restrict__ vtlo,
    float* __restrict__ rpartT, float* __restrict__ invl) {
  __shared__ u16 Kh[32 * 256], Kl[32 * 256];
  __shared__ u16 Vh[256 * 32], Vl[256 * 32];
  __shared__ u16 Pb[4][2][16 * 40];
  const int t = threadIdx.x;
  const int w = t >> 6, l = t & 63;
  const int lr = l & 15, lk = l >> 4;
  // XCD-cluster swizzle: all 36 blocks of one km land on xcd = km%8.
  const int L = blockIdx.x;
  const int xcd = L & 7, slot = L >> 3;
  const int km = xcd + 8 * (slot / 36);
  const int inner = slot % 36;
  const int b = inner & 3, qb = inner >> 2;
  const int qw = qb * 64 + w * 16;

  bf16x8 qh[8], ql[8];
  {
    const u16* ph = qhi + ((size_t)(b * 576 + qw + lr)) * 256 + lk * 8;
    const u16* pl = qlo + ((size_t)(b * 576 + qw + lr)) * 256 + lk * 8;
#pragma unroll
    for (int s = 0; s < 8; ++s) {
      qh[s] = *(const bf16x8*)(ph + s * 32);
      ql[s] = *(const bf16x8*)(pl + s * 32);
    }
  }

  f32x4 o[16];
#pragma unroll
  for (int i = 0; i < 16; ++i) o[i] = {};
  float m_part[4] = {-1e30f, -1e30f, -1e30f, -1e30f};
  float l_part[4] = {0.f, 0.f, 0.f, 0.f};

  const size_t kbase = (size_t)km * 576 * 256;

  // staging geometry (per-thread, 4 chunks each of K and V, hi+lo)
  int krow[4], kgc[4], kdst[4], vd[4], vgc[4], vdst[4];
#pragma unroll
  for (int i = 0; i < 4; ++i) {
    int ch = t + i * 256;
    krow[i] = ch >> 5;
    kgc[i] = ch & 31;
    kdst[i] = krow[i] * 256 + (kgc[i] ^ (krow[i] & 7)) * 8;
    vd[i] = ch >> 2;
    vgc[i] = ch & 3;
    vdst[i] = vd[i] * 32 + ((vgc[i] + (vd[i] >> 1)) & 3) * 8;
  }
  bf16x8 sKh[4], sKl[4], sVh[4], sVl[4];
#pragma unroll
  for (int i = 0; i < 4; ++i) {
    sKh[i] = *(const bf16x8*)(khi + kbase + (size_t)krow[i] * 256 + kgc[i] * 8);
    sKl[i] = *(const bf16x8*)(klo + kbase + (size_t)krow[i] * 256 + kgc[i] * 8);
    sVh[i] = *(const bf16x8*)(vthi + kbase + (size_t)vd[i] * 576 + vgc[i] * 8);
    sVl[i] = *(const bf16x8*)(vtlo + kbase + (size_t)vd[i] * 576 + vgc[i] * 8);
  }

  u16* phw = &Pb[w][0][0];
  u16* plw = &Pb[w][1][0];
  const int x0 = lr & 7;

  for (int kt = 0; kt < 18; ++kt) {
    __syncthreads();
#pragma unroll
    for (int i = 0; i < 4; ++i) {
      *(bf16x8*)(Kh + kdst[i]) = sKh[i];
      *(bf16x8*)(Kl + kdst[i]) = sKl[i];
      *(bf16x8*)(Vh + vdst[i]) = sVh[i];
      *(bf16x8*)(Vl + vdst[i]) = sVl[i];
    }
    if (kt < 17) {
      const int j0n = kt * 32 + 32;
#pragma unroll
      for (int i = 0; i < 4; ++i) {
        sKh[i] = *(const bf16x8*)(khi + kbase + (size_t)(j0n + krow[i]) * 256 + kgc[i] * 8);
        sKl[i] = *(const bf16x8*)(klo + kbase + (size_t)(j0n + krow[i]) * 256 + kgc[i] * 8);
        sVh[i] = *(const bf16x8*)(vthi + kbase + (size_t)vd[i] * 576 + j0n + vgc[i] * 8);
        sVl[i] = *(const bf16x8*)(vtlo + kbase + (size_t)vd[i] * 576 + j0n + vgc[i] * 8);
      }
    }
    __syncthreads();

    f32x4 s0 = {}, s1 = {};
    __builtin_amdgcn_s_setprio(1);
#pragma unroll
    for (int s = 0; s < 8; ++s) {
      int cl = s * 4 + lk;
      bf16x8 bh0 = *(const bf16x8*)(Kh + lr * 256 + (cl ^ x0) * 8);
      bf16x8 bl0 = *(const bf16x8*)(Kl + lr * 256 + (cl ^ x0) * 8);
      bf16x8 bh1 = *(const bf16x8*)(Kh + (lr + 16) * 256 + (cl ^ x0) * 8);
      bf16x8 bl1 = *(const bf16x8*)(Kl + (lr + 16) * 256 + (cl ^ x0) * 8);
      s0 = MFMA16(qh[s], bh0, s0);
      s0 = MFMA16(qh[s], bl0, s0);
      s0 = MFMA16(ql[s], bh0, s0);
      s1 = MFMA16(qh[s], bh1, s1);
      s1 = MFMA16(qh[s], bl1, s1);
      s1 = MFMA16(ql[s], bh1, s1);
    }
    __builtin_amdgcn_s_setprio(0);

#pragma unroll
    for (int r = 0; r < 4; ++r) {
      float a0 = s0[r] * SCALE, a1 = s1[r] * SCALE;
      m_part[r] = fmaxf(m_part[r], fmaxf(a0, a1));
      float e0 = __expf(a0), e1 = __expf(a1);
      l_part[r] += e0 + e1;
      int row = lk * 4 + r;
      u16 h0 = f2bf(e0);
      u16 h1 = f2bf(e1);
      phw[row * 40 + lr] = h0;
      phw[row * 40 + lr + 16] = h1;
      plw[row * 40 + lr] = f2bf(e0 - bf2f(h0));
      plw[row * 40 + lr + 16] = f2bf(e1 - bf2f(h1));
    }
    bf16x8 pah = *(const bf16x8*)(phw + lr * 40 + lk * 8);
    bf16x8 pal = *(const bf16x8*)(plw + lr * 40 + lk * 8);
    __builtin_amdgcn_s_setprio(1);
#pragma unroll
    for (int fd = 0; fd < 16; ++fd) {
      int d = lr + 16 * fd;
      int cp = (lk + (d >> 1)) & 3;
      bf16x8 vh_ = *(const bf16x8*)(Vh + d * 32 + cp * 8);
      bf16x8 vl_ = *(const bf16x8*)(Vl + d * 32 + cp * 8);
      o[fd] = MFMA16(pah, vh_, o[fd]);
      o[fd] = MFMA16(pah, vl_, o[fd]);
      o[fd] = MFMA16(pal, vh_, o[fd]);
    }
    __builtin_amdgcn_s_setprio(0);
  }

  float inv4[4], stat4[4];
#pragma unroll
  for (int r = 0; r < 4; ++r) {
    float lv = l_part[r], mv = m_part[r];
    lv += __shfl_xor(lv, 1, 64); mv = fmaxf(mv, __shfl_xor(mv, 1, 64));
    lv += __shfl_xor(lv, 2, 64); mv = fmaxf(mv, __shfl_xor(mv, 2, 64));
    lv += __shfl_xor(lv, 4, 64); mv = fmaxf(mv, __shfl_xor(mv, 4, 64));
    lv += __shfl_xor(lv, 8, 64); mv = fmaxf(mv, __shfl_xor(mv, 8, 64));
    inv4[r] = 1.0f / lv;
    stat4[r] = __expf(mv) * inv4[r];  // = 1/l_ref (softmax-normalized)
  }
  float* dst = rpartT + (size_t)(b * 80 + km) * (256 * 576);
#pragma unroll
  for (int fd = 0; fd < 16; ++fd) {
    int d = lr + 16 * fd;
    f32x4 vv;
    vv[0] = o[fd][0] * inv4[0];
    vv[1] = o[fd][1] * inv4[1];
    vv[2] = o[fd][2] * inv4[2];
    vv[3] = o[fd][3] * inv4[3];
    *(f32x4*)(dst + (size_t)d * 576 + qw + lk * 4) = vv;
  }
  if (lr == 0) {
#pragma unroll
    for (int r = 0; r < 4; ++r)
      invl[(size_t)(b * 80 + km) * 576 + qw + lk * 4 + r] = stat4[r];
  }
}

// ---------------------------------------------------------------------------
// Weights: s[b,k,m] = mean_n 1/l_ref ; w = gate(p) * s / (sum_m s + 1e-8)
// ---------------------------------------------------------------------------
__global__ __launch_bounds__(256) void weight_kernel(const float* __restrict__ invl,
                                                     const float* __restrict__ p,
                                                     float* __restrict__ wout) {
  const int k = blockIdx.x, b = blockIdx.y;
  __shared__ float sm[10];
  __shared__ float red[4];
  const int t = threadIdx.x;
  for (int m = 0; m < 10; ++m) {
    float part = 0.f;
    for (int n = t; n < 576; n += 256)
      part += invl[(size_t)((b * 8 + k) * 10 + m) * 576 + n];
#pragma unroll
    for (int off = 32; off; off >>= 1) part += __shfl_down(part, off, 64);
    if ((t & 63) == 0) red[t >> 6] = part;
    __syncthreads();
    if (t == 0) sm[m] = (red[0] + red[1] + red[2] + red[3]) * (1.0f / 576.0f);
    __syncthreads();
  }
  if (t == 0) {
    float tot = 0.f;
    for (int m = 0; m < 10; ++m) tot += sm[m];
    float pmax = fmaxf(fmaxf(p[0 * 8 + k], p[1 * 8 + k]), fmaxf(p[2 * 8 + k], p[3 * 8 + k]));
    float gate = (pmax >= 0.01f) ? p[b * 8 + k] : 0.0f;
    for (int m = 0; m < 10; ++m)
      wout[(b * 8 + k) * 10 + m] = gate * sm[m] / (tot + 1e-8f);
  }
}

// ---------------------------------------------------------------------------
// out[b][d][n] = sum_km w[b,km] * rpartT[b,km][d][n]
// ---------------------------------------------------------------------------
__global__ __launch_bounds__(256) void reduce_out_k(const float* __restrict__ rpartT,
                                                    const float* __restrict__ wbuf,
                                                    float* __restrict__ out) {
  int idx = blockIdx.x * 256 + threadIdx.x;
  int b = idx / 147456;
  size_t off = (size_t)(idx % 147456);
  const float* base = rpartT + (size_t)b * 80 * 147456 + off;
  const float* wp = wbuf + b * 80;
  float acc = 0.f;
#pragma unroll 8
  for (int g = 0; g < 80; ++g) acc += wp[g] * base[(size_t)g * 147456];
  out[idx] = acc;
}

// ---------------------------------------------------------------------------
extern "C" void kernel_launch(void* const* d_in, const int* in_sizes, int n_in,
                              void* d_out, int out_size, void* d_ws, size_t ws_size,
                              hipStream_t stream) {
  const float* Q = (const float*)d_in[0];
  const float* dbk = (const float*)d_in[1];
  const float* dbv = (const float*)d_in[2];
  const float* p = (const float*)d_in[3];
  const float* Wq = (const float*)d_in[4];
  const float* Wk = (const float*)d_in[5];
  const float* Wv = (const float*)d_in[6];
  float* out = (float*)d_out;
  char* ws = (char*)d_ws;

  u16* qhi = (u16*)(ws);
  u16* qlo = (u16*)(ws + 1179648);
  u16* khi = (u16*)(ws + 2359296);
  u16* klo = (u16*)(ws + 25952256);
  u16* vthi = (u16*)(ws + 49545216);
  u16* vtlo = (u16*)(ws + 73138176);
  float* invl = (float*)(ws + 96731136);
  float* wbuf = (float*)(ws + 97468416);
  float* rpartT = (float*)(ws + 97469696);
  u16* wqh = (u16*)(ws + 97469696);
  u16* wql = wqh + 106496;
  u16* wkh = wql + 106496;
  u16* wkl = wkh + 106496;
  u16* wvh = wkl + 106496;
  u16* wvl = wvh + 98304;

  convert_w<<<1216, 256, 0, stream>>>(Wq, Wk, Wv, wqh, wql, wkh, wkl, wvh, wvl);
  proj_mfma<416, false><<<36, 256, 0, stream>>>(Q, wqh, wql, qhi, qlo);
  proj_mfma<416, false><<<720, 256, 0, stream>>>(dbk, wkh, wkl, khi, klo);
  proj_mfma<384, true><<<720, 256, 0, stream>>>(dbv, wvh, wvl, vthi, vtlo);
  attn_kernel<<<2880, 256, 0, stream>>>(qhi, qlo, khi, klo, vthi, vtlo, rpartT, invl);
  weight_kernel<<<dim3(8, 4), 256, 0, stream>>>(invl, p, wbuf);
  reduce_out_k<<<2304, 256, 0, stream>>>(rpartT, wbuf, out);
}